// Round 7
// baseline (118.669 us; speedup 1.0000x reference)
//
#include <hip/hip_runtime.h>
#include <math.h>

// Renderer: occupancy-field ray marching + secant + shading.
// R7: one ray per 128-thread block (2 waves) -> 8192 waves = 8 waves/SIMD.
//     Wave 0: phase-1 steps 0..63, phase-3 samples 0..63 (full H), compositing.
//     Wave 1: phase-1 steps 64..127, phase-3 samples 64..95 (H split across
//     lane halves + shfl_xor(32)), publishes segB pixels via LDS.
//     Phase 2 + secant duplicated in both waves (wave-uniform, barrier-free).
//     Packed-f32 math + exp2/poly softplus as R6.

namespace {

constexpr int H_    = 128;
constexpr int RS    = 128;   // RAY_STEPS
constexpr int NSEC  = 8;
constexpr int SOUT_ = 32;    // STEPS_OUT
constexpr int SIN_  = 64;    // STEPS_IN
constexpr int FULL_ = 96;
constexpr float EPSA   = 1e-6f;
constexpr float DELTA_ = 0.44626032029685964f; // max(2*exp(-1.5), 0.1)
constexpr float L2E    = 1.4426950408889634f;  // log2(e)
constexpr float LN2    = 0.6931471805599453f;

typedef __attribute__((ext_vector_type(2))) float f2;

__device__ __forceinline__ f2 s2(float v) { return f2{v, v}; }

// deg-6 poly for log2(1+e), e in [0,1], via t = 2e-1; max err ~1e-4.
constexpr float PC0 =  0.5849625007211562f;
constexpr float PC1 =  0.4808983469629878f;
constexpr float PC2 = -0.0801497244938313f;
constexpr float PC3 =  0.0178110498875181f;
constexpr float PC4 = -0.0044527624718795f;
constexpr float PC5 =  0.0011873633258345f;
constexpr float PC6 = -0.0003298231460651f;

// packed log2-domain softplus: sp2(u) = max(u,0) + log2(1 + 2^-|u|)
__device__ __forceinline__ f2 sp2p(f2 u) {
    f2 e;
    e.x = __builtin_amdgcn_exp2f(-fabsf(u.x));
    e.y = __builtin_amdgcn_exp2f(-fabsf(u.y));
    f2 t = e + e - 1.0f;
    f2 p = s2(PC6);
    p = __builtin_elementwise_fma(p, t, s2(PC5));
    p = __builtin_elementwise_fma(p, t, s2(PC4));
    p = __builtin_elementwise_fma(p, t, s2(PC3));
    p = __builtin_elementwise_fma(p, t, s2(PC2));
    p = __builtin_elementwise_fma(p, t, s2(PC1));
    p = __builtin_elementwise_fma(p, t, s2(PC0));
    return __builtin_elementwise_max(u, s2(0.0f)) + p;
}

__device__ __forceinline__ float sigmoid_fast(float x) {
    return __builtin_amdgcn_rcpf(1.0f + __expf(-x));
}
__device__ __forceinline__ float sgnf(float p) {
    return (p > 0.0f) ? 1.0f : ((p < 0.0f) ? -1.0f : 0.0f);
}
__device__ __forceinline__ float secant_step(float f_l, float f_h, float d_l, float d_h) {
    float den = f_h - f_l;
    if (fabsf(den) > 1e-12f) return -f_l * (d_h - d_l) / den + d_l;
    return 0.5f * (d_l + d_h);
}

__device__ void inv4(const float* m, float* o) {
    float inv[16];
    inv[0]  =  m[5]*m[10]*m[15] - m[5]*m[11]*m[14] - m[9]*m[6]*m[15] + m[9]*m[7]*m[14] + m[13]*m[6]*m[11] - m[13]*m[7]*m[10];
    inv[4]  = -m[4]*m[10]*m[15] + m[4]*m[11]*m[14] + m[8]*m[6]*m[15] - m[8]*m[7]*m[14] - m[12]*m[6]*m[11] + m[12]*m[7]*m[10];
    inv[8]  =  m[4]*m[9]*m[15]  - m[4]*m[11]*m[13] - m[8]*m[5]*m[15] + m[8]*m[7]*m[13] + m[12]*m[5]*m[11] - m[12]*m[7]*m[9];
    inv[12] = -m[4]*m[9]*m[14]  + m[4]*m[10]*m[13] + m[8]*m[5]*m[14] - m[8]*m[6]*m[13] - m[12]*m[5]*m[10] + m[12]*m[6]*m[9];
    inv[1]  = -m[1]*m[10]*m[15] + m[1]*m[11]*m[14] + m[9]*m[2]*m[15] - m[9]*m[3]*m[14] - m[13]*m[2]*m[11] + m[13]*m[3]*m[10];
    inv[5]  =  m[0]*m[10]*m[15] - m[0]*m[11]*m[14] - m[8]*m[2]*m[15] + m[8]*m[3]*m[14] + m[12]*m[2]*m[11] - m[12]*m[3]*m[10];
    inv[9]  = -m[0]*m[9]*m[15]  + m[0]*m[11]*m[13] + m[8]*m[1]*m[15] - m[8]*m[3]*m[13] - m[12]*m[1]*m[11] + m[12]*m[3]*m[9];
    inv[13] =  m[0]*m[9]*m[14]  - m[0]*m[10]*m[13] - m[8]*m[1]*m[14] + m[8]*m[2]*m[13] + m[12]*m[1]*m[10] - m[12]*m[2]*m[9];
    inv[2]  =  m[1]*m[6]*m[15]  - m[1]*m[7]*m[14]  - m[5]*m[2]*m[15] + m[5]*m[3]*m[14] + m[13]*m[2]*m[7]  - m[13]*m[3]*m[6];
    inv[6]  = -m[0]*m[6]*m[15]  + m[0]*m[7]*m[14]  + m[4]*m[2]*m[15] - m[4]*m[3]*m[14] - m[12]*m[2]*m[7]  + m[12]*m[3]*m[6];
    inv[10] =  m[0]*m[5]*m[15]  - m[0]*m[7]*m[13]  - m[4]*m[1]*m[15] + m[4]*m[3]*m[13] + m[12]*m[1]*m[7]  - m[12]*m[3]*m[5];
    inv[14] = -m[0]*m[5]*m[14]  + m[0]*m[6]*m[13]  + m[4]*m[1]*m[14] - m[4]*m[2]*m[13] - m[12]*m[1]*m[6]  + m[12]*m[2]*m[5];
    inv[3]  = -m[1]*m[6]*m[11]  + m[1]*m[7]*m[10]  + m[5]*m[2]*m[11] - m[5]*m[3]*m[10] - m[9]*m[2]*m[7]   + m[9]*m[3]*m[6];
    inv[7]  =  m[0]*m[6]*m[11]  - m[0]*m[7]*m[10]  - m[4]*m[2]*m[11] + m[4]*m[3]*m[10] + m[8]*m[2]*m[7]   - m[8]*m[3]*m[6];
    inv[11] = -m[0]*m[5]*m[11]  + m[0]*m[7]*m[9]   + m[4]*m[1]*m[11] - m[4]*m[3]*m[9]  - m[8]*m[1]*m[7]   + m[8]*m[3]*m[5];
    inv[15] =  m[0]*m[5]*m[10]  - m[0]*m[6]*m[9]   - m[4]*m[1]*m[10] + m[4]*m[2]*m[9]  + m[8]*m[1]*m[6]   - m[8]*m[2]*m[5];
    float det = m[0]*inv[0] + m[1]*inv[4] + m[2]*inv[8] + m[3]*inv[12];
    float idet = 1.0f / det;
    for (int i = 0; i < 16; i++) o[i] = inv[i] * idet;
}

__global__ __launch_bounds__(128, 8) void render_k(
    const float* __restrict__ pixels,
    const float* __restrict__ Cm, const float* __restrict__ Wm, const float* __restrict__ Sm,
    const float* __restrict__ W1, const float* __restrict__ b1,
    const float* __restrict__ W2, const float* __restrict__ b2,
    const float* __restrict__ Wc1, const float* __restrict__ bc1,
    const float* __restrict__ Wc2, const float* __restrict__ bc2,
    float* __restrict__ out, int N)
{
    const int tid  = threadIdx.x;     // 0..127
    const int lane = tid & 63;
    const int wv   = tid >> 6;        // wave id 0/1
    const int r    = blockIdx.x;      // one ray per block

    // pair-major weight LDS: slot j2 holds hidden units 2*j2, 2*j2+1
    __shared__ float4 sP0[H_/2];      // {a,a', c,c'}       (occ, log2 domain)
    __shared__ float4 sP1[H_/2];      // {w,w', aC,aC'}     (w = w2*ln2)
    __shared__ float4 sP2[H_/2];      // {cC,cC', w0,w0'}
    __shared__ float4 sP3[H_/2];      // {w1,w1', w2,w2'}
    __shared__ float  sval[RS];       // phase-1 logits
    __shared__ float4 sPixB[32];      // segB pixels {r,g,b,alpha}
    __shared__ float  sInv[3][16];    // iC, iW, iS
    __shared__ float  sT[16], sM[16];

    // ---- geometry: one inv4 per matrix on lanes 0..2 ----
    {
        const float* mm = (tid == 0) ? Cm : ((tid == 1) ? Wm : Sm);
        float o[16];
        inv4(mm, o);
        if (tid < 3)
            for (int k = 0; k < 16; k++) sInv[tid][k] = o[k];
    }
    __syncthreads();
    if (tid < 16) {                   // T = iW @ iC
        int row = tid >> 2, col = tid & 3;
        float s = 0.0f;
        for (int k = 0; k < 4; k++) s += sInv[1][row*4 + k] * sInv[0][k*4 + col];
        sT[tid] = s;
    }
    __syncthreads();
    if (tid < 16) {                   // M = iS @ T
        int row = tid >> 2, col = tid & 3;
        float s = 0.0f;
        for (int k = 0; k < 4; k++) s += sInv[2][row*4 + k] * sT[k*4 + col];
        sM[tid] = s;
    }
    __syncthreads();

    float cx, cy, cz, rx, ry, rz, dfar;
    int mint;
    {
        const float px_ = pixels[2*r], py_ = pixels[2*r + 1];
        float cam[3], dir[3];
        for (int i = 0; i < 3; i++) {
            cam[i] = sM[4*i + 3];
            float pw = sM[4*i + 0]*px_ + sM[4*i + 1]*py_ + sM[4*i + 2] + sM[4*i + 3];
            dir[i] = pw - cam[i];
        }
        float nrm = sqrtf(dir[0]*dir[0] + dir[1]*dir[1] + dir[2]*dir[2]);
        rx = dir[0]/nrm; ry = dir[1]/nrm; rz = dir[2]/nrm;
        cx = cam[0]; cy = cam[1]; cz = cam[2];
        float rcd = rx*cx + ry*cy + rz*cz;
        float cc  = cx*cx + cy*cy + cz*cz;
        float under = rcd*rcd - (cc - 1.0f);      // RADIUS = 1
        mint = under > 0.0f;
        float s = sqrtf(mint ? under : 1.0f);
        dfar = mint ? fmaxf(s - rcd, 0.0f) : 0.0f;
    }

    // ---- staging + reparam: thread tid stages hidden unit u = tid ----
    {
        const int u = tid;
        float w1x = W1[u], w1y = W1[H_ + u], w1z = W1[2*H_ + u];
        float b1j = b1[u], w2j = W2[u];
        float a = (w1x*rx + w1y*ry + w1z*rz) * L2E;
        float c = (w1x*cx + w1y*cy + w1z*cz + b1j) * L2E;
        float w = w2j * LN2;
        float q0 = Wc1[u],        q1 = Wc1[H_ + u],  q2 = Wc1[2*H_ + u];
        float q3 = Wc1[3*H_ + u], q4 = Wc1[4*H_ + u], q5 = Wc1[5*H_ + u];
        float aC = q0*rx + q1*ry + q2*rz;
        float cC = q0*cx + q1*cy + q2*cz + bc1[u] - (q3*rx + q4*ry + q5*rz);
        float w0 = Wc2[3*u + 0], w1c = Wc2[3*u + 1], w2c = Wc2[3*u + 2];
        const int j2 = u >> 1;
        if ((u & 1) == 0) {
            sP0[j2].x = a;  sP0[j2].z = c;
            sP1[j2].x = w;  sP1[j2].z = aC;
            sP2[j2].x = cC; sP2[j2].z = w0;
            sP3[j2].x = w1c; sP3[j2].z = w2c;
        } else {
            sP0[j2].y = a;  sP0[j2].w = c;
            sP1[j2].y = w;  sP1[j2].w = aC;
            sP2[j2].y = cC; sP2[j2].w = w0;
            sP3[j2].y = w1c; sP3[j2].w = w2c;
        }
    }
    const float b2v  = b2[0];
    const float bc20 = bc2[0], bc21 = bc2[1], bc22 = bc2[2];
    __syncthreads();

    float alpha0 = 0.0f, r0c = 0.0f, g0c = 0.0f, b0c = 0.0f;  // wave0: sample lane

    if (dfar == 0.0f) {
        // ---- fast path: all 96 samples at the camera point (both waves) ----
        float4 q0 = sP0[lane];
        float4 q1 = sP1[lane];
        float4 q2 = sP2[lane];
        float4 q3 = sP3[lane];
        f2 sp = sp2p(f2{q0.z, q0.w});
        float part = sp.x*q1.x + sp.y*q1.y;
        f2 ff = __builtin_elementwise_max(f2{q2.x, q2.y}, s2(0.0f));
        float A0 = ff.x*q2.z + ff.y*q2.w;
        float A1 = ff.x*q3.x + ff.y*q3.y;
        float A2 = ff.x*q3.z + ff.y*q3.w;
#pragma unroll
        for (int off = 32; off; off >>= 1) {
            part += __shfl_xor(part, off, 64);
            A0   += __shfl_xor(A0,   off, 64);
            A1   += __shfl_xor(A1,   off, 64);
            A2   += __shfl_xor(A2,   off, 64);
        }
        alpha0 = sigmoid_fast(part + b2v);
        r0c = sigmoid_fast(A0 + bc20);
        g0c = sigmoid_fast(A1 + bc21);
        b0c = sigmoid_fast(A2 + bc22);
        if (wv == 1 && lane < 32)
            sPixB[lane] = make_float4(r0c, g0c, b0c, alpha0);
    } else {
        // ---- phase 1: step s = tid, one sample/lane, H paired ----
        const float inv127 = 1.0f / (RS - 1);
        {
            const f2 dd = s2(dfar * ((float)tid * inv127));
            f2 acc = s2(0.0f);
#pragma unroll 4
            for (int j2 = 0; j2 < H_/2; j2++) {
                float4 q0 = sP0[j2];
                float4 q1 = sP1[j2];
                f2 u = __builtin_elementwise_fma(f2{q0.x, q0.y}, dd, f2{q0.z, q0.w});
                acc = __builtin_elementwise_fma(sp2p(u), f2{q1.x, q1.y}, acc);
            }
            sval[tid] = acc.x + acc.y + b2v;
        }
        __syncthreads();

        // ---- phase 2 + secant: duplicated in both waves (wave-uniform) ----
        float dnp, dfp;
        int obj;
        {
            float va = sigmoid_fast(sval[lane])      - 0.5f;
            float vb = sigmoid_fast(sval[lane + 64]) - 0.5f;
            float van = __shfl_down(va, 1, 64);
            float vb0 = __shfl(vb, 0, 64);
            if (lane == 63) van = vb0;
            float vbn = __shfl_down(vb, 1, 64);
            float ca = sgnf(va * van) * (float)(RS - lane);
            float cb = (lane < 63) ? sgnf(vb * vbn) * (float)(64 - lane) : 1.0f;
            float cmin = ca; int ind = lane;
            if (cb < cmin) { cmin = cb; ind = lane + 64; }
#pragma unroll
            for (int off = 32; off; off >>= 1) {
                float c2 = __shfl_xor(cmin, off, 64);
                int   i2 = __shfl_xor(ind,  off, 64);
                if (c2 < cmin || (c2 == cmin && i2 < ind)) { cmin = c2; ind = i2; }
            }
            const int mask_0_free = (__shfl(va, 0, 64) < 0.0f);
            const int mask_sc = cmin < 0.0f;
            const int ind_hi = min(ind + 1, RS - 1);
            const float f_low  = sigmoid_fast(sval[ind])    - 0.5f;
            const float f_high = sigmoid_fast(sval[ind_hi]) - 0.5f;
            const float d_low  = dfar * ((float)ind    * inv127);
            const float d_high = dfar * ((float)ind_hi * inv127);
            const int msk = mask_sc && (f_low < 0.0f) && mint && mask_0_free;

            float d_p = secant_step(f_low, f_high, d_low, d_high);
            if (msk) {   // wave-uniform
                float4 q0 = sP0[lane];
                float4 q1 = sP1[lane];
                const f2 a2 = f2{q0.x, q0.y};
                const f2 c2v = f2{q0.z, q0.w};
                const f2 w2 = f2{q1.x, q1.y};
                float d_l = d_low, f_l = f_low, d_h = d_high, f_h = f_high;
                for (int it = 0; it < NSEC; it++) {
                    f2 u2 = __builtin_elementwise_fma(a2, s2(d_p), c2v);
                    f2 sp = sp2p(u2);
                    float part = sp.x*w2.x + sp.y*w2.y;
#pragma unroll
                    for (int off = 32; off; off >>= 1) part += __shfl_xor(part, off, 64);
                    float fm = sigmoid_fast(part + b2v) - 0.5f;
                    bool low = fm < 0.0f;
                    d_l = low ? d_p : d_l;  f_l = low ? fm : f_l;
                    d_h = low ? d_h : d_p;  f_h = low ? f_h : fm;
                    d_p = secant_step(f_l, f_h, d_l, d_h);
                }
            }
            float d_i;
            if (!mask_0_free)      d_i = 0.0f;
            else if (msk)          d_i = d_p;
            else                   d_i = INFINITY;
            int mask_zero = (d_i == 0.0f);
            int mask_pred = isfinite(d_i);
            float dists = mask_pred ? d_i : 1.0f;
            if (mask_zero) dists = 0.0f;
            obj = mask_pred && !mask_zero;
            dnp = fmaxf(dists - DELTA_, 0.0f);
            dfp = fminf(dists + DELTA_, dfar);
        }

        auto sample_d = [&](int s) -> float {
            if (obj) {
                if (s < SOUT_) return dnp * ((float)s * (1.0f / (SOUT_ - 1)));
                float u = (float)(s - SOUT_) * (1.0f / (SIN_ - 1));
                return dnp * (1.0f - u) + dfp * u;
            }
            return dfar * ((float)s * (1.0f / (FULL_ - 1)));
        };

        if (wv == 0) {
            // ---- phase 3 / wave 0: samples 0..63, full H ----
            const f2 dd = s2(sample_d(lane));
            f2 SO = s2(0.0f), A0 = s2(0.0f), A1 = s2(0.0f), A2 = s2(0.0f);
#pragma unroll 4
            for (int j2 = 0; j2 < H_/2; j2++) {
                float4 q0 = sP0[j2];
                float4 q1 = sP1[j2];
                float4 q2 = sP2[j2];
                float4 q3 = sP3[j2];
                f2 u = __builtin_elementwise_fma(f2{q0.x, q0.y}, dd, f2{q0.z, q0.w});
                SO = __builtin_elementwise_fma(sp2p(u), f2{q1.x, q1.y}, SO);
                f2 f = __builtin_elementwise_max(
                           __builtin_elementwise_fma(f2{q1.z, q1.w}, dd, f2{q2.x, q2.y}),
                           s2(0.0f));
                A0 = __builtin_elementwise_fma(f, f2{q2.z, q2.w}, A0);
                A1 = __builtin_elementwise_fma(f, f2{q3.x, q3.y}, A1);
                A2 = __builtin_elementwise_fma(f, f2{q3.z, q3.w}, A2);
            }
            alpha0 = sigmoid_fast(SO.x + SO.y + b2v);
            r0c = sigmoid_fast(A0.x + A0.y + bc20);
            g0c = sigmoid_fast(A1.x + A1.y + bc21);
            b0c = sigmoid_fast(A2.x + A2.y + bc22);
        } else {
            // ---- phase 3 / wave 1: samples 64..95, H split by lane half ----
            const int s1 = 64 + (lane & 31);
            const int jb = (lane >> 5) * (H_/4);   // 0 or 32 pair-slots
            const f2 dd = s2(sample_d(s1));
            f2 SO = s2(0.0f), A0 = s2(0.0f), A1 = s2(0.0f), A2 = s2(0.0f);
#pragma unroll 4
            for (int j2 = jb; j2 < jb + H_/4; j2++) {
                float4 q0 = sP0[j2];
                float4 q1 = sP1[j2];
                float4 q2 = sP2[j2];
                float4 q3 = sP3[j2];
                f2 u = __builtin_elementwise_fma(f2{q0.x, q0.y}, dd, f2{q0.z, q0.w});
                SO = __builtin_elementwise_fma(sp2p(u), f2{q1.x, q1.y}, SO);
                f2 f = __builtin_elementwise_max(
                           __builtin_elementwise_fma(f2{q1.z, q1.w}, dd, f2{q2.x, q2.y}),
                           s2(0.0f));
                A0 = __builtin_elementwise_fma(f, f2{q2.z, q2.w}, A0);
                A1 = __builtin_elementwise_fma(f, f2{q3.x, q3.y}, A1);
                A2 = __builtin_elementwise_fma(f, f2{q3.z, q3.w}, A2);
            }
            float SOs = SO.x + SO.y, A0s = A0.x + A0.y;
            float A1s = A1.x + A1.y, A2s = A2.x + A2.y;
            SOs += __shfl_xor(SOs, 32, 64);
            A0s += __shfl_xor(A0s, 32, 64);
            A1s += __shfl_xor(A1s, 32, 64);
            A2s += __shfl_xor(A2s, 32, 64);
            if (lane < 32) {
                sPixB[lane] = make_float4(sigmoid_fast(A0s + bc20),
                                          sigmoid_fast(A1s + bc21),
                                          sigmoid_fast(A2s + bc22),
                                          sigmoid_fast(SOs + b2v));
            }
        }
    }
    __syncthreads();

    // ---- compositing: wave 0 only; segA in regs, segB from LDS ----
    if (wv == 0) {
        float mA = 1.0f - alpha0 + EPSA;
        float p = mA;
#pragma unroll
        for (int off = 1; off < 64; off <<= 1) {
            float v = __shfl_up(p, off, 64);
            if (lane >= off) p *= v;
        }
        float TexA = __shfl_up(p, 1, 64);
        if (lane == 0) TexA = 1.0f;
        float TA = __shfl(p, 63, 64);
        float wA = alpha0 * TexA;

        float rB = 0.0f, gB = 0.0f, bB = 0.0f, aB = 0.0f;
        if (lane < 32) {
            float4 P = sPixB[lane];
            rB = P.x; gB = P.y; bB = P.z; aB = P.w;
        }
        float mB = (lane < 32) ? (1.0f - aB + EPSA) : 1.0f;
        float pb = mB;
#pragma unroll
        for (int off = 1; off < 32; off <<= 1) {
            float v = __shfl_up(pb, off, 64);
            if (lane >= off) pb *= v;
        }
        float TexB = __shfl_up(pb, 1, 64);
        if (lane == 0) TexB = 1.0f;
        float wB = (lane < 32) ? aB * TexB * TA : 0.0f;

        float s0 = wA*r0c + wB*rB;
        float s1 = wA*g0c + wB*gB;
        float s2v = wA*b0c + wB*bB;
#pragma unroll
        for (int off = 32; off; off >>= 1) {
            s0  += __shfl_xor(s0,  off, 64);
            s1  += __shfl_xor(s1,  off, 64);
            s2v += __shfl_xor(s2v, off, 64);
        }
        if (lane == 0) {
            out[3*r + 0] = s0;
            out[3*r + 1] = s1;
            out[3*r + 2] = s2v;
        }
    }
}

} // namespace

extern "C" void kernel_launch(void* const* d_in, const int* in_sizes, int n_in,
                              void* d_out, int out_size, void* d_ws, size_t ws_size,
                              hipStream_t stream) {
    const float* pixels = (const float*)d_in[0];
    const float* Cm  = (const float*)d_in[1];
    const float* Wm  = (const float*)d_in[2];
    const float* Sm  = (const float*)d_in[3];
    const float* W1  = (const float*)d_in[4];
    const float* b1  = (const float*)d_in[5];
    const float* W2  = (const float*)d_in[6];
    const float* b2  = (const float*)d_in[7];
    const float* Wc1 = (const float*)d_in[8];
    const float* bc1 = (const float*)d_in[9];
    const float* Wc2 = (const float*)d_in[10];
    const float* bc2 = (const float*)d_in[11];
    float* out = (float*)d_out;

    const int N = in_sizes[0] / 2;   // pixels is (B=1, N, 2)
    hipLaunchKernelGGL(render_k, dim3(N), dim3(128), 0, stream,
                       pixels, Cm, Wm, Sm, W1, b1, W2, b2, Wc1, bc1, Wc2, bc2, out, N);
}